// Round 4
// baseline (1355.163 us; speedup 1.0000x reference)
//
#include <hip/hip_runtime.h>
#include <cstddef>
#include <cstdint>

#define B_ 64
#define T_ 800
#define D_ 80
#define H_ 128
#define G_ 512   // 4*H
#define K_ 39

typedef _Float16 h2_t __attribute__((ext_vector_type(2)));

__device__ __forceinline__ float fdot2_(h2_t a, h2_t b, float c) {
#if __has_builtin(__builtin_amdgcn_fdot2)
  return __builtin_amdgcn_fdot2(a, b, c, false);
#else
  return c + (float)a.x * (float)b.x + (float)a.y * (float)b.y;
#endif
}

__device__ __forceinline__ h2_t asH2_(float f) { return __builtin_bit_cast(h2_t, f); }

__device__ __forceinline__ float sigf_(float x) {
  return 1.0f / (1.0f + __expf(-x));
}
__device__ __forceinline__ float tanhf_(float x) {
  return 2.0f / (1.0f + __expf(-2.0f * x)) - 1.0f;
}

// lane-broadcast: readlane with literal index (VALU, no LDS, no barrier)
__device__ __forceinline__ float laneb_(float v, int lane) {
  return __builtin_bit_cast(float, __builtin_amdgcn_readlane(__builtin_bit_cast(int, v), lane));
}

// ---------------------------------------------------------------------------
// xw[dir][bt][r] (f16) = x[bt][:] . Wih_dir[r][:]
// Thread owns W rows (2*tid, 2*tid+1) f16x2 register-resident (80 VGPRs).
// x tile (128 bt-rows) staged once in LDS as f16; all reads broadcast.
// ---------------------------------------------------------------------------
__global__ __launch_bounds__(256)
void xw_kernel(const float* __restrict__ x,
               const float* __restrict__ Wih_f, const float* __restrict__ Wih_b,
               _Float16* __restrict__ xw)
{
  const int dir  = blockIdx.x & 1;
  const int tile = blockIdx.x >> 1;      // 0..399
  const float* W = dir ? Wih_b : Wih_f;
  const int tid  = threadIdx.x;

  h2_t wa[D_ / 2], wb[D_ / 2];
  {
    const float* ra = W + (size_t)(2 * tid) * D_;
    const float* rb = ra + D_;
    #pragma unroll
    for (int i = 0; i < D_ / 2; ++i) {
      h2_t v; v.x = (_Float16)ra[2 * i]; v.y = (_Float16)ra[2 * i + 1]; wa[i] = v;
      h2_t u; u.x = (_Float16)rb[2 * i]; u.y = (_Float16)rb[2 * i + 1]; wb[i] = u;
    }
  }

  __shared__ alignas(16) _Float16 xsh[128 * D_];   // 20 KB
  const int bt0 = tile * 128;
  {
    const float4* src = (const float4*)(x + (size_t)bt0 * D_);
    h2_t* dst = (h2_t*)xsh;
    for (int i = tid; i < 128 * D_ / 4; i += 256) {
      float4 v = src[i];
      h2_t p0; p0.x = (_Float16)v.x; p0.y = (_Float16)v.y;
      h2_t p1; p1.x = (_Float16)v.z; p1.y = (_Float16)v.w;
      dst[2 * i]     = p0;
      dst[2 * i + 1] = p1;
    }
  }
  __syncthreads();

  _Float16* outb = xw + ((size_t)dir * B_ * T_ + bt0) * G_ + 2 * tid;
  for (int row = 0; row < 128; ++row) {
    const float4* xr4 = (const float4*)(xsh + row * D_);   // 10 chunks of 4 h2
    float s0 = 0.f, s1 = 0.f, s2 = 0.f, s3 = 0.f;
    #pragma unroll
    for (int ch = 0; ch < 10; ++ch) {
      float4 f = xr4[ch];
      h2_t q0 = asH2_(f.x), q1 = asH2_(f.y), q2 = asH2_(f.z), q3 = asH2_(f.w);
      s0 = fdot2_(wa[4 * ch],     q0, s0);
      s1 = fdot2_(wa[4 * ch + 1], q1, s1);
      s0 = fdot2_(wa[4 * ch + 2], q2, s0);
      s1 = fdot2_(wa[4 * ch + 3], q3, s1);
      s2 = fdot2_(wb[4 * ch],     q0, s2);
      s3 = fdot2_(wb[4 * ch + 1], q1, s3);
      s2 = fdot2_(wb[4 * ch + 2], q2, s2);
      s3 = fdot2_(wb[4 * ch + 3], q3, s3);
    }
    h2_t o; o.x = (_Float16)(s0 + s1); o.y = (_Float16)(s2 + s3);
    *(h2_t*)(outb + (size_t)row * G_) = o;   // 4B store, lanes contiguous
  }
}

// ---------------------------------------------------------------------------
// Recurrent LSTM. TWO (b,dir) pairs per 512-thread WG (grid 64) -> 2 waves
// per SIMD for latency hiding. Within a pair (256 threads): thread
// (u=tid&127, hi=tid>>7) owns gate rows (256*hi+u, 256*hi+128+u); Whh rows
// f16x2 register-resident. h read from LDS as float4 (ds_read_b128 broadcast).
// ---------------------------------------------------------------------------
template<int USE_XW>
__global__ __launch_bounds__(512, 2)
void lstm_kernel(const float* __restrict__ x,
                 const float* __restrict__ Wih_f, const float* __restrict__ Whh_f,
                 const float* __restrict__ bih_f, const float* __restrict__ bhh_f,
                 const float* __restrict__ Wih_b, const float* __restrict__ Whh_b,
                 const float* __restrict__ bih_b, const float* __restrict__ bhh_b,
                 const _Float16* __restrict__ xw,
                 _Float16* __restrict__ hcat)
{
  const int tid = threadIdx.x;
  const int p   = tid >> 8;                 // pair slot 0/1
  const int t8  = tid & 255;
  const int u   = t8 & 127;
  const int hi  = t8 >> 7;
  const int gp  = blockIdx.x * 2 + p;       // 0..127 (dir uniform per block)
  const int bb  = gp & 63;
  const int dir = gp >> 6;

  const float* Whh = dir ? Whh_b : Whh_f;
  const float* Wih = dir ? Wih_b : Wih_f;
  const float* bih = dir ? bih_b : bih_f;
  const float* bhh = dir ? bhh_b : bhh_f;

  const int r0 = hi * 256 + u;
  const int r1 = r0 + 128;

  h2_t w0[H_ / 2], w1[H_ / 2];
  #pragma unroll
  for (int j = 0; j < H_ / 2; ++j) {
    const float* a = Whh + (size_t)r0 * H_ + 2 * j;
    const float* d = Whh + (size_t)r1 * H_ + 2 * j;
    h2_t v0; v0.x = (_Float16)a[0]; v0.y = (_Float16)a[1]; w0[j] = v0;
    h2_t v1; v1.x = (_Float16)d[0]; v1.y = (_Float16)d[1]; w1[j] = v1;
  }
  h2_t wx0[D_ / 2], wx1[D_ / 2];
  if (!USE_XW) {
    #pragma unroll
    for (int i = 0; i < D_ / 2; ++i) {
      const float* a = Wih + (size_t)r0 * D_ + 2 * i;
      const float* d = Wih + (size_t)r1 * D_ + 2 * i;
      h2_t v0; v0.x = (_Float16)a[0]; v0.y = (_Float16)a[1]; wx0[i] = v0;
      h2_t v1; v1.x = (_Float16)d[0]; v1.y = (_Float16)d[1]; wx1[i] = v1;
    }
  }
  const float bias0 = bih[r0] + bhh[r0];
  const float bias1 = bih[r1] + bhh[r1];

  __shared__ alignas(16) _Float16 hs[2][H_];
  __shared__ float gos[2][2][H_];
  __shared__ alignas(16) _Float16 xs[2][D_];

  if (t8 < H_) hs[p][t8] = (_Float16)0.0f;
  float c = 0.0f;

  const float*    xb  = x + (size_t)bb * T_ * D_;
  const _Float16* xwb = xw + ((size_t)dir * B_ * T_ + (size_t)bb * T_) * G_;
  _Float16*       hb  = hcat + (size_t)bb * T_ * (2 * H_) + dir * H_;

  const int t0 = dir ? (T_ - 1) : 0;
  _Float16 xw0p = (_Float16)0.0f, xw1p = (_Float16)0.0f;
  if (USE_XW) {
    xw0p = xwb[(size_t)t0 * G_ + r0];
    xw1p = xwb[(size_t)t0 * G_ + r1];
  } else {
    if (t8 < D_) xs[p][t8] = (_Float16)xb[t0 * D_ + t8];
  }
  __syncthreads();

  for (int tt = 0; tt < T_; ++tt) {
    const int t  = dir ? (T_ - 1 - tt) : tt;
    const int tn = dir ? (t - 1) : (t + 1);

    float a0 = bias0, a1 = bias1, b0 = 0.0f, b1 = 0.0f;
    float xn = 0.0f;
    if (USE_XW) {
      a0 += (float)xw0p;
      a1 += (float)xw1p;
      if (tt + 1 < T_) {                    // prefetch next step's xw
        xw0p = xwb[(size_t)tn * G_ + r0];
        xw1p = xwb[(size_t)tn * G_ + r1];
      }
    } else {
      if (tt + 1 < T_ && hi == 1 && u < D_) xn = xb[tn * D_ + u];
      const float4* xr4 = (const float4*)xs[p];
      #pragma unroll
      for (int ch = 0; ch < D_ / 8; ++ch) {
        float4 f = xr4[ch];
        h2_t q0 = asH2_(f.x), q1 = asH2_(f.y), q2 = asH2_(f.z), q3 = asH2_(f.w);
        a0 = fdot2_(wx0[4 * ch],     q0, a0);
        b0 = fdot2_(wx0[4 * ch + 1], q1, b0);
        a0 = fdot2_(wx0[4 * ch + 2], q2, a0);
        b0 = fdot2_(wx0[4 * ch + 3], q3, b0);
        a1 = fdot2_(wx1[4 * ch],     q0, a1);
        b1 = fdot2_(wx1[4 * ch + 1], q1, b1);
        a1 = fdot2_(wx1[4 * ch + 2], q2, a1);
        b1 = fdot2_(wx1[4 * ch + 3], q3, b1);
      }
    }

    const float4* hp4 = (const float4*)hs[p];   // 16 chunks of 4 h2
    #pragma unroll
    for (int ch = 0; ch < H_ / 8; ++ch) {
      float4 f = hp4[ch];
      h2_t q0 = asH2_(f.x), q1 = asH2_(f.y), q2 = asH2_(f.z), q3 = asH2_(f.w);
      a0 = fdot2_(w0[4 * ch],     q0, a0);
      b0 = fdot2_(w0[4 * ch + 1], q1, b0);
      a0 = fdot2_(w0[4 * ch + 2], q2, a0);
      b0 = fdot2_(w0[4 * ch + 3], q3, b0);
      a1 = fdot2_(w1[4 * ch],     q0, a1);
      b1 = fdot2_(w1[4 * ch + 1], q1, b1);
      a1 = fdot2_(w1[4 * ch + 2], q2, a1);
      b1 = fdot2_(w1[4 * ch + 3], q3, b1);
    }
    const float g0 = a0 + b0;   // row r0 (i or g)
    const float g1 = a1 + b1;   // row r1 (f or o)

    if (hi) { gos[p][0][u] = g0; gos[p][1][u] = g1; }
    __syncthreads();           // g,o visible; this step's hs/xs reads done

    if (!hi) {
      const float gi = g0, gf = g1;
      const float gg = gos[p][0][u], go = gos[p][1][u];
      c = sigf_(gf) * c + sigf_(gi) * tanhf_(gg);
      const float h = sigf_(go) * tanhf_(c);
      hs[p][u] = (_Float16)h;
      hb[(size_t)t * (2 * H_) + u] = (_Float16)h;
    } else if (!USE_XW) {
      if (tt + 1 < T_ && u < D_) xs[p][u] = (_Float16)xn;
    }
    __syncthreads();           // new hs (and xs) ready
  }
}

// ---------------------------------------------------------------------------
// Emissions from f16 hcat. 64 bt-rows per block; h tile in LDS (stride 257),
// Wp in LDS (wave-uniform broadcast).
// ---------------------------------------------------------------------------
__global__ __launch_bounds__(256)
void emis_kernel(const _Float16* __restrict__ hcat,
                 const float* __restrict__ Wp, const float* __restrict__ bp,
                 float* __restrict__ em)
{
  __shared__ float sh[64 * 257];
  __shared__ float swp[40 * 256];
  const int tid = threadIdx.x;

  for (int i = tid; i < K_ * 256; i += 256) swp[i] = Wp[i];

  const h2_t* src = (const h2_t*)(hcat + (size_t)blockIdx.x * 64 * 256);
  for (int i = tid; i < 64 * 128; i += 256) {
    h2_t v = src[i];
    int row = i >> 7, col = (i & 127) * 2;
    sh[row * 257 + col]     = (float)v.x;
    sh[row * 257 + col + 1] = (float)v.y;
  }
  __syncthreads();

  const int row = tid & 63;
  const int kq  = tid >> 6;          // wave-uniform
  const float* hrow = &sh[row * 257];

  float accs[10];
  #pragma unroll
  for (int q = 0; q < 10; ++q) {
    int k = kq * 10 + q;
    accs[q] = (k < K_) ? bp[k] : 0.0f;
  }

  for (int j0 = 0; j0 < 256; j0 += 4) {
    float h0 = hrow[j0], h1 = hrow[j0 + 1], hh2 = hrow[j0 + 2], h3 = hrow[j0 + 3];
    #pragma unroll
    for (int q = 0; q < 10; ++q) {
      const float4 w = *(const float4*)&swp[(kq * 10 + q) * 256 + j0];
      accs[q] += h0 * w.x + h1 * w.y + hh2 * w.z + h3 * w.w;
    }
  }

  const size_t bt = (size_t)blockIdx.x * 64 + row;
  #pragma unroll
  for (int q = 0; q < 10; ++q) {
    int k = kq * 10 + q;
    if (k < K_) em[bt * K_ + k] = accs[q];
  }
}

// ---------------------------------------------------------------------------
// Numerator: masked reduction over t per batch element.
// ---------------------------------------------------------------------------
__global__ void crf_num_kernel(const int* __restrict__ labels, const int* __restrict__ lengths,
                               const float* __restrict__ em,
                               const float* __restrict__ start_t, const float* __restrict__ end_t,
                               const float* __restrict__ trans,
                               float* __restrict__ num)
{
  const int b = blockIdx.x;
  const int tid = threadIdx.x;   // 256
  const int len = lengths[b];
  float acc = 0.0f;
  for (int t = 1 + tid; t < len; t += 256) {
    int lp = labels[b * T_ + t - 1];
    int lc = labels[b * T_ + t];
    acc += trans[lp * K_ + lc] + em[((size_t)b * T_ + t) * K_ + lc];
  }
  __shared__ float red[256];
  red[tid] = acc;
  __syncthreads();
  for (int s = 128; s > 0; s >>= 1) {
    if (tid < s) red[tid] += red[tid + s];
    __syncthreads();
  }
  if (tid == 0) {
    int l0 = labels[b * T_];
    int ll = labels[b * T_ + len - 1];
    num[b] = red[0] + start_t[l0] + em[(size_t)b * T_ * K_ + l0] + end_t[ll];
  }
}

// ---------------------------------------------------------------------------
// Denominator: linear-space forward algorithm, one wave per batch element.
// State v_k per lane; per step: v'_k = (sum_j readlane(v,j)*et[j][k])*exp(em).
// et column register-resident (39 VGPRs). NO LDS, NO barriers in the loop;
// renormalize every 4 steps via lane shuffles.
// ---------------------------------------------------------------------------
__global__ void crf_den_kernel(const float* __restrict__ em, const int* __restrict__ lengths,
                               const float* __restrict__ start_t, const float* __restrict__ end_t,
                               const float* __restrict__ trans,
                               float* __restrict__ den)
{
  const int b = blockIdx.x;
  const int k = threadIdx.x;     // 64 threads = 1 wave

  float et[K_];
  #pragma unroll
  for (int j = 0; j < K_; ++j)
    et[j] = (k < K_) ? __expf(trans[j * K_ + k]) : 0.0f;

  const int len = lengths[b];
  const float* emb = em + (size_t)b * T_ * K_;

  float a0 = (k < K_) ? (start_t[k] + emb[k]) : -1e30f;
  float m = a0;
  #pragma unroll
  for (int off = 32; off > 0; off >>= 1) m = fmaxf(m, __shfl_xor(m, off));
  float v = __expf(a0 - m);           // lanes >= 39 -> 0
  float off_acc = m;

  float emn = 0.0f;
  if (k < K_ && len > 1) emn = emb[K_ + k];

  for (int t = 1; t < len; ++t) {
    const float emc = emn;
    const int tp = (t + 1 < len) ? (t + 1) : (len - 1);
    emn = (k < K_) ? emb[(size_t)tp * K_ + k] : 0.0f;   // prefetch

    const float pv = v;
    float s0 = 0.f, s1 = 0.f, s2 = 0.f, s3 = 0.f;
    #pragma unroll
    for (int j = 0; j < 36; j += 4) {
      s0 = fmaf(laneb_(pv, j),     et[j],     s0);
      s1 = fmaf(laneb_(pv, j + 1), et[j + 1], s1);
      s2 = fmaf(laneb_(pv, j + 2), et[j + 2], s2);
      s3 = fmaf(laneb_(pv, j + 3), et[j + 3], s3);
    }
    s0 = fmaf(laneb_(pv, 36), et[36], s0);
    s1 = fmaf(laneb_(pv, 37), et[37], s1);
    s2 = fmaf(laneb_(pv, 38), et[38], s2);

    v = ((s0 + s1) + (s2 + s3)) * __expf(emc);
    if ((t & 3) == 0) {               // renormalize every 4 steps
      float vm = v;
      #pragma unroll
      for (int off = 32; off > 0; off >>= 1) vm = fmaxf(vm, __shfl_xor(vm, off));
      v *= 1.0f / vm;
      off_acc += __logf(vm);
    }
  }

  float w = (k < K_) ? v * __expf(end_t[k]) : 0.0f;
  #pragma unroll
  for (int off = 32; off > 0; off >>= 1) w += __shfl_xor(w, off);
  if (k == 0) den[b] = off_acc + __logf(w);
}

__global__ void finalize_kernel(const float* __restrict__ num, const float* __restrict__ den,
                                float* __restrict__ out)
{
  const int tid = threadIdx.x;   // 64
  float v = den[tid] - num[tid];
  #pragma unroll
  for (int off = 32; off > 0; off >>= 1) v += __shfl_down(v, off);
  if (tid == 0) out[0] = v * (1.0f / 64.0f);
}

extern "C" void kernel_launch(void* const* d_in, const int* in_sizes, int n_in,
                              void* d_out, int out_size, void* d_ws, size_t ws_size,
                              hipStream_t stream)
{
  (void)in_sizes; (void)n_in; (void)out_size;
  const float* features = (const float*)d_in[0];
  const int*   lengths  = (const int*)d_in[1];
  const int*   labels   = (const int*)d_in[2];
  const float* Wih_f = (const float*)d_in[3];
  const float* Whh_f = (const float*)d_in[4];
  const float* bih_f = (const float*)d_in[5];
  const float* bhh_f = (const float*)d_in[6];
  const float* Wih_b = (const float*)d_in[7];
  const float* Whh_b = (const float*)d_in[8];
  const float* bih_b = (const float*)d_in[9];
  const float* bhh_b = (const float*)d_in[10];
  const float* Wp      = (const float*)d_in[11];
  const float* bp      = (const float*)d_in[12];
  const float* start_t = (const float*)d_in[13];
  const float* end_t   = (const float*)d_in[14];
  const float* trans   = (const float*)d_in[15];
  float* out = (float*)d_out;

  // ws layout (bytes): hcat f16 [0, 26214400) ; em f32 [26214400, +7987200) ;
  // num/den 512 B ; xw f16 [34202112, +104857600) if ws is big enough.
  char* wsc = (char*)d_ws;
  _Float16* hcatH = (_Float16*)wsc;
  float*    em    = (float*)(wsc + 26214400);
  float*    num   = (float*)(wsc + 26214400 + 7987200);
  float*    den   = num + B_;
  _Float16* xwH   = (_Float16*)(wsc + 34202112);
  const bool big  = ws_size >= (size_t)34202112 + 104857600;

  if (big) {
    hipLaunchKernelGGL(xw_kernel, dim3(2 * B_ * T_ / 128), dim3(256), 0, stream,
                       features, Wih_f, Wih_b, xwH);
    hipLaunchKernelGGL((lstm_kernel<1>), dim3(B_), dim3(512), 0, stream,
                       features, Wih_f, Whh_f, bih_f, bhh_f,
                       Wih_b, Whh_b, bih_b, bhh_b, xwH, hcatH);
  } else {
    hipLaunchKernelGGL((lstm_kernel<0>), dim3(B_), dim3(512), 0, stream,
                       features, Wih_f, Whh_f, bih_f, bhh_f,
                       Wih_b, Whh_b, bih_b, bhh_b, xwH, hcatH);
  }
  hipLaunchKernelGGL(emis_kernel, dim3(B_ * T_ / 64), dim3(256), 0, stream,
                     hcatH, Wp, bp, em);
  hipLaunchKernelGGL(crf_num_kernel, dim3(B_), dim3(256), 0, stream,
                     labels, lengths, em, start_t, end_t, trans, num);
  hipLaunchKernelGGL(crf_den_kernel, dim3(B_), dim3(64), 0, stream,
                     em, lengths, start_t, end_t, trans, den);
  hipLaunchKernelGGL(finalize_kernel, dim3(1), dim3(64), 0, stream,
                     num, den, out);
}

// Round 5
// 1167.617 us; speedup vs baseline: 1.1606x; 1.1606x over previous
//
#include <hip/hip_runtime.h>
#include <cstddef>
#include <cstdint>

#define B_ 64
#define T_ 800
#define D_ 80
#define H_ 128
#define G_ 512   // 4*H
#define K_ 39

typedef _Float16 h2_t __attribute__((ext_vector_type(2)));

__device__ __forceinline__ float fdot2_(h2_t a, h2_t b, float c) {
#if __has_builtin(__builtin_amdgcn_fdot2)
  return __builtin_amdgcn_fdot2(a, b, c, false);
#else
  return c + (float)a.x * (float)b.x + (float)a.y * (float)b.y;
#endif
}

__device__ __forceinline__ h2_t asH2_(float f) { return __builtin_bit_cast(h2_t, f); }

__device__ __forceinline__ float sigf_(float x) {
  return 1.0f / (1.0f + __expf(-x));
}
__device__ __forceinline__ float tanhf_(float x) {
  return 2.0f / (1.0f + __expf(-2.0f * x)) - 1.0f;   // saturates correctly
}

// lane-broadcast: readlane with literal index (VALU, no LDS, no barrier)
__device__ __forceinline__ float laneb_(float v, int lane) {
  return __builtin_bit_cast(float, __builtin_amdgcn_readlane(__builtin_bit_cast(int, v), lane));
}

// ---------------------------------------------------------------------------
// Recurrent LSTM, fused x-projection. Grid 128 = one WG per (b,dir) on 128
// CUs; 512 threads = 8 waves = 2 waves/SIMD. Thread owns ONE gate row
// r = gt*128+u (gt = tid>>7: 0=i 1=f 2=g 3=o — wave-uniform), with Whh row
// (64 h2) + Wih row (40 h2) register-resident (~104 VGPRs).
// Per step: dots -> per-gate partial nonlinearity (parallel) -> barrier ->
// o-group: c update + h (short chain) -> barrier. h global stores are
// register-buffered 8 steps and flushed post-barrier (avoids the per-step
// vmcnt(0) store drain at s_barrier).
// ---------------------------------------------------------------------------
__global__ __launch_bounds__(512, 2)
void lstm_kernel(const float* __restrict__ x,
                 const float* __restrict__ Wih_f, const float* __restrict__ Whh_f,
                 const float* __restrict__ bih_f, const float* __restrict__ bhh_f,
                 const float* __restrict__ Wih_b, const float* __restrict__ Whh_b,
                 const float* __restrict__ bih_b, const float* __restrict__ bhh_b,
                 _Float16* __restrict__ hcat)
{
  const int bb  = blockIdx.x & 63;
  const int dir = blockIdx.x >> 6;
  const float* Whh = dir ? Whh_b : Whh_f;
  const float* Wih = dir ? Wih_b : Wih_f;
  const float* bih = dir ? bih_b : bih_f;
  const float* bhh = dir ? bhh_b : bhh_f;

  const int tid = threadIdx.x;
  const int u   = tid & 127;
  const int gt  = tid >> 7;        // 0=i 1=f 2=g 3=o (uniform per wave)
  const int r   = gt * H_ + u;

  h2_t wh[H_ / 2];
  h2_t wx[D_ / 2];
  {
    const float* hr = Whh + (size_t)r * H_;
    #pragma unroll
    for (int j = 0; j < H_ / 2; ++j) {
      h2_t v; v.x = (_Float16)hr[2 * j]; v.y = (_Float16)hr[2 * j + 1]; wh[j] = v;
    }
    const float* xr = Wih + (size_t)r * D_;
    #pragma unroll
    for (int i = 0; i < D_ / 2; ++i) {
      h2_t v; v.x = (_Float16)xr[2 * i]; v.y = (_Float16)xr[2 * i + 1]; wx[i] = v;
    }
  }
  const float bias = bih[r] + bhh[r];

  __shared__ alignas(16) _Float16 hs[H_];
  __shared__ alignas(16) _Float16 xs[D_];
  __shared__ float si[H_], sf[H_], tg[H_];

  if (tid < H_) hs[tid] = (_Float16)0.0f;
  float c = 0.0f;                  // gt==3 owns the cell state
  _Float16 hbuf[8];

  const float* xb = x + (size_t)bb * T_ * D_;
  _Float16* hb = hcat + (size_t)bb * T_ * (2 * H_) + dir * H_;

  const int t0 = dir ? (T_ - 1) : 0;
  if (tid < D_) xs[tid] = (_Float16)xb[t0 * D_ + tid];
  __syncthreads();

  for (int tb = 0; tb < T_; tb += 8) {
    // Flush previous 8 buffered h values (o-group). Issued right after the
    // step boundary so the stores have a full step to drain before the next
    // barrier's vmcnt(0).
    if (gt == 3 && tb) {
      #pragma unroll
      for (int q = 0; q < 8; ++q) {
        const int ts = tb - 8 + q;
        const int tq = dir ? (T_ - 1 - ts) : ts;
        hb[(size_t)tq * (2 * H_) + u] = hbuf[q];
      }
    }

    #pragma unroll
    for (int q = 0; q < 8; ++q) {
      const int tt = tb + q;
      const int t  = dir ? (T_ - 1 - tt) : tt;
      const int tn = dir ? (t - 1) : (t + 1);

      // x prefetch for next step (i-group lanes u<80; idle post-barrier)
      float xn = 0.0f;
      if (gt == 0 && u < D_ && tt + 1 < T_) xn = xb[tn * D_ + u];

      float a0 = bias, a1 = 0.f, a2 = 0.f, a3 = 0.f;
      const float4* xr4 = (const float4*)xs;     // 10 chunks of 4 h2
      #pragma unroll
      for (int ch = 0; ch < D_ / 8; ++ch) {
        float4 f = xr4[ch];
        a0 = fdot2_(wx[4 * ch],     asH2_(f.x), a0);
        a1 = fdot2_(wx[4 * ch + 1], asH2_(f.y), a1);
        a2 = fdot2_(wx[4 * ch + 2], asH2_(f.z), a2);
        a3 = fdot2_(wx[4 * ch + 3], asH2_(f.w), a3);
      }
      const float4* hr4 = (const float4*)hs;     // 16 chunks of 4 h2
      #pragma unroll
      for (int ch = 0; ch < H_ / 8; ++ch) {
        float4 f = hr4[ch];
        a0 = fdot2_(wh[4 * ch],     asH2_(f.x), a0);
        a1 = fdot2_(wh[4 * ch + 1], asH2_(f.y), a1);
        a2 = fdot2_(wh[4 * ch + 2], asH2_(f.z), a2);
        a3 = fdot2_(wh[4 * ch + 3], asH2_(f.w), a3);
      }
      const float g = (a0 + a1) + (a2 + a3);

      // per-gate partial nonlinearity, parallel across gate groups
      float so = 0.0f;
      if (gt == 0)      si[u] = sigf_(g);
      else if (gt == 1) sf[u] = sigf_(g);
      else if (gt == 2) tg[u] = tanhf_(g);
      else              so    = sigf_(g);
      __syncthreads();   // partials visible; this step's hs/xs reads done

      if (gt == 3) {
        c = sf[u] * c + si[u] * tg[u];
        const float h = so * tanhf_(c);
        hs[u]   = (_Float16)h;
        hbuf[q] = (_Float16)h;
      } else if (gt == 0) {
        if (u < D_ && tt + 1 < T_) xs[u] = (_Float16)xn;
      }
      __syncthreads();   // new hs/xs ready
    }
  }

  // final flush (steps T-8..T-1)
  if (gt == 3) {
    #pragma unroll
    for (int q = 0; q < 8; ++q) {
      const int ts = T_ - 8 + q;
      const int tq = dir ? (T_ - 1 - ts) : ts;
      hb[(size_t)tq * (2 * H_) + u] = hbuf[q];
    }
  }
}

// ---------------------------------------------------------------------------
// Emissions from f16 hcat. 64 bt-rows per block; h tile in LDS (stride 257),
// Wp in LDS (wave-uniform broadcast).
// ---------------------------------------------------------------------------
__global__ __launch_bounds__(256)
void emis_kernel(const _Float16* __restrict__ hcat,
                 const float* __restrict__ Wp, const float* __restrict__ bp,
                 float* __restrict__ em)
{
  __shared__ float sh[64 * 257];
  __shared__ float swp[40 * 256];
  const int tid = threadIdx.x;

  for (int i = tid; i < K_ * 256; i += 256) swp[i] = Wp[i];

  const h2_t* src = (const h2_t*)(hcat + (size_t)blockIdx.x * 64 * 256);
  for (int i = tid; i < 64 * 128; i += 256) {
    h2_t v = src[i];
    int row = i >> 7, col = (i & 127) * 2;
    sh[row * 257 + col]     = (float)v.x;
    sh[row * 257 + col + 1] = (float)v.y;
  }
  __syncthreads();

  const int row = tid & 63;
  const int kq  = tid >> 6;          // wave-uniform
  const float* hrow = &sh[row * 257];

  float accs[10];
  #pragma unroll
  for (int q = 0; q < 10; ++q) {
    int k = kq * 10 + q;
    accs[q] = (k < K_) ? bp[k] : 0.0f;
  }

  for (int j0 = 0; j0 < 256; j0 += 4) {
    float h0 = hrow[j0], h1 = hrow[j0 + 1], hh2 = hrow[j0 + 2], h3 = hrow[j0 + 3];
    #pragma unroll
    for (int q = 0; q < 10; ++q) {
      const float4 w = *(const float4*)&swp[(kq * 10 + q) * 256 + j0];
      accs[q] += h0 * w.x + h1 * w.y + hh2 * w.z + h3 * w.w;
    }
  }

  const size_t bt = (size_t)blockIdx.x * 64 + row;
  #pragma unroll
  for (int q = 0; q < 10; ++q) {
    int k = kq * 10 + q;
    if (k < K_) em[bt * K_ + k] = accs[q];
  }
}

// ---------------------------------------------------------------------------
// Numerator: masked reduction over t per batch element.
// ---------------------------------------------------------------------------
__global__ void crf_num_kernel(const int* __restrict__ labels, const int* __restrict__ lengths,
                               const float* __restrict__ em,
                               const float* __restrict__ start_t, const float* __restrict__ end_t,
                               const float* __restrict__ trans,
                               float* __restrict__ num)
{
  const int b = blockIdx.x;
  const int tid = threadIdx.x;   // 256
  const int len = lengths[b];
  float acc = 0.0f;
  for (int t = 1 + tid; t < len; t += 256) {
    int lp = labels[b * T_ + t - 1];
    int lc = labels[b * T_ + t];
    acc += trans[lp * K_ + lc] + em[((size_t)b * T_ + t) * K_ + lc];
  }
  __shared__ float red[256];
  red[tid] = acc;
  __syncthreads();
  for (int s = 128; s > 0; s >>= 1) {
    if (tid < s) red[tid] += red[tid + s];
    __syncthreads();
  }
  if (tid == 0) {
    int l0 = labels[b * T_];
    int ll = labels[b * T_ + len - 1];
    num[b] = red[0] + start_t[l0] + em[(size_t)b * T_ * K_ + l0] + end_t[ll];
  }
}

// ---------------------------------------------------------------------------
// Denominator: linear-space forward algorithm, one wave per batch element.
// State v_k per lane; per step: v'_k = (sum_j readlane(v,j)*et[j][k])*exp(em).
// et column register-resident (39 VGPRs). No LDS, no barriers in the loop;
// renormalize every 4 steps via lane shuffles.
// ---------------------------------------------------------------------------
__global__ void crf_den_kernel(const float* __restrict__ em, const int* __restrict__ lengths,
                               const float* __restrict__ start_t, const float* __restrict__ end_t,
                               const float* __restrict__ trans,
                               float* __restrict__ den)
{
  const int b = blockIdx.x;
  const int k = threadIdx.x;     // 64 threads = 1 wave

  float et[K_];
  #pragma unroll
  for (int j = 0; j < K_; ++j)
    et[j] = (k < K_) ? __expf(trans[j * K_ + k]) : 0.0f;

  const int len = lengths[b];
  const float* emb = em + (size_t)b * T_ * K_;

  float a0 = (k < K_) ? (start_t[k] + emb[k]) : -1e30f;
  float m = a0;
  #pragma unroll
  for (int off = 32; off > 0; off >>= 1) m = fmaxf(m, __shfl_xor(m, off));
  float v = __expf(a0 - m);           // lanes >= 39 -> 0
  float off_acc = m;

  float emn = 0.0f;
  if (k < K_ && len > 1) emn = emb[K_ + k];

  for (int t = 1; t < len; ++t) {
    const float emc = emn;
    const int tp = (t + 1 < len) ? (t + 1) : (len - 1);
    emn = (k < K_) ? emb[(size_t)tp * K_ + k] : 0.0f;   // prefetch

    const float pv = v;
    float s0 = 0.f, s1 = 0.f, s2 = 0.f, s3 = 0.f;
    #pragma unroll
    for (int j = 0; j < 36; j += 4) {
      s0 = fmaf(laneb_(pv, j),     et[j],     s0);
      s1 = fmaf(laneb_(pv, j + 1), et[j + 1], s1);
      s2 = fmaf(laneb_(pv, j + 2), et[j + 2], s2);
      s3 = fmaf(laneb_(pv, j + 3), et[j + 3], s3);
    }
    s0 = fmaf(laneb_(pv, 36), et[36], s0);
    s1 = fmaf(laneb_(pv, 37), et[37], s1);
    s2 = fmaf(laneb_(pv, 38), et[38], s2);

    v = ((s0 + s1) + (s2 + s3)) * __expf(emc);
    if ((t & 3) == 0) {               // renormalize every 4 steps
      float vm = v;
      #pragma unroll
      for (int off = 32; off > 0; off >>= 1) vm = fmaxf(vm, __shfl_xor(vm, off));
      v *= 1.0f / vm;
      off_acc += __logf(vm);
    }
  }

  float w = (k < K_) ? v * __expf(end_t[k]) : 0.0f;
  #pragma unroll
  for (int off = 32; off > 0; off >>= 1) w += __shfl_xor(w, off);
  if (k == 0) den[b] = off_acc + __logf(w);
}

__global__ void finalize_kernel(const float* __restrict__ num, const float* __restrict__ den,
                                float* __restrict__ out)
{
  const int tid = threadIdx.x;   // 64
  float v = den[tid] - num[tid];
  #pragma unroll
  for (int off = 32; off > 0; off >>= 1) v += __shfl_down(v, off);
  if (tid == 0) out[0] = v * (1.0f / 64.0f);
}

extern "C" void kernel_launch(void* const* d_in, const int* in_sizes, int n_in,
                              void* d_out, int out_size, void* d_ws, size_t ws_size,
                              hipStream_t stream)
{
  (void)in_sizes; (void)n_in; (void)out_size; (void)ws_size;
  const float* features = (const float*)d_in[0];
  const int*   lengths  = (const int*)d_in[1];
  const int*   labels   = (const int*)d_in[2];
  const float* Wih_f = (const float*)d_in[3];
  const float* Whh_f = (const float*)d_in[4];
  const float* bih_f = (const float*)d_in[5];
  const float* bhh_f = (const float*)d_in[6];
  const float* Wih_b = (const float*)d_in[7];
  const float* Whh_b = (const float*)d_in[8];
  const float* bih_b = (const float*)d_in[9];
  const float* bhh_b = (const float*)d_in[10];
  const float* Wp      = (const float*)d_in[11];
  const float* bp      = (const float*)d_in[12];
  const float* start_t = (const float*)d_in[13];
  const float* end_t   = (const float*)d_in[14];
  const float* trans   = (const float*)d_in[15];
  float* out = (float*)d_out;

  // ws layout (bytes): hcat f16 [0, 26214400) ; em f32 [26214400, +7987200) ;
  // num/den 512 B after that.
  char* wsc = (char*)d_ws;
  _Float16* hcatH = (_Float16*)wsc;
  float*    em    = (float*)(wsc + 26214400);
  float*    num   = (float*)(wsc + 26214400 + 7987200);
  float*    den   = num + B_;

  hipLaunchKernelGGL(lstm_kernel, dim3(2 * B_), dim3(512), 0, stream,
                     features, Wih_f, Whh_f, bih_f, bhh_f,
                     Wih_b, Whh_b, bih_b, bhh_b, hcatH);
  hipLaunchKernelGGL(emis_kernel, dim3(B_ * T_ / 64), dim3(256), 0, stream,
                     hcatH, Wp, bp, em);
  hipLaunchKernelGGL(crf_num_kernel, dim3(B_), dim3(256), 0, stream,
                     labels, lengths, em, start_t, end_t, trans, num);
  hipLaunchKernelGGL(crf_den_kernel, dim3(B_), dim3(64), 0, stream,
                     em, lengths, start_t, end_t, trans, den);
  hipLaunchKernelGGL(finalize_kernel, dim3(1), dim3(64), 0, stream,
                     num, den, out);
}

// Round 6
// 1034.228 us; speedup vs baseline: 1.3103x; 1.1290x over previous
//
#include <hip/hip_runtime.h>
#include <cstddef>
#include <cstdint>

#define B_ 64
#define T_ 800
#define D_ 80
#define H_ 128
#define G_ 512   // 4*H
#define K_ 39

typedef _Float16 h2_t __attribute__((ext_vector_type(2)));

__device__ __forceinline__ float fdot2_(h2_t a, h2_t b, float c) {
#if __has_builtin(__builtin_amdgcn_fdot2)
  return __builtin_amdgcn_fdot2(a, b, c, false);
#else
  return c + (float)a.x * (float)b.x + (float)a.y * (float)b.y;
#endif
}

__device__ __forceinline__ h2_t asH2_(float f) { return __builtin_bit_cast(h2_t, f); }

__device__ __forceinline__ float sigf_(float x) {
  return 1.0f / (1.0f + __expf(-x));
}
__device__ __forceinline__ float tanhf_(float x) {
  return 2.0f / (1.0f + __expf(-2.0f * x)) - 1.0f;   // saturates correctly
}

__device__ __forceinline__ float laneb_(float v, int lane) {
  return __builtin_bit_cast(float, __builtin_amdgcn_readlane(__builtin_bit_cast(int, v), lane));
}

// ---------------------------------------------------------------------------
// xw[dir][bt][r] (f16) = x[bt][:] . Wih_dir[r][:]
// Thread owns W rows (2*tid, 2*tid+1) f16x2 register-resident (80 VGPRs).
// x tile (128 bt-rows) staged once in LDS as f16; all reads broadcast.
// ---------------------------------------------------------------------------
__global__ __launch_bounds__(256)
void xw_kernel(const float* __restrict__ x,
               const float* __restrict__ Wih_f, const float* __restrict__ Wih_b,
               _Float16* __restrict__ xw)
{
  const int dir  = blockIdx.x & 1;
  const int tile = blockIdx.x >> 1;      // 0..399
  const float* W = dir ? Wih_b : Wih_f;
  const int tid  = threadIdx.x;

  h2_t wa[D_ / 2], wb[D_ / 2];
  {
    const float* ra = W + (size_t)(2 * tid) * D_;
    const float* rb = ra + D_;
    #pragma unroll
    for (int i = 0; i < D_ / 2; ++i) {
      h2_t v; v.x = (_Float16)ra[2 * i]; v.y = (_Float16)ra[2 * i + 1]; wa[i] = v;
      h2_t u; u.x = (_Float16)rb[2 * i]; u.y = (_Float16)rb[2 * i + 1]; wb[i] = u;
    }
  }

  __shared__ alignas(16) _Float16 xsh[128 * D_];   // 20 KB
  const int bt0 = tile * 128;
  {
    const float4* src = (const float4*)(x + (size_t)bt0 * D_);
    h2_t* dst = (h2_t*)xsh;
    for (int i = tid; i < 128 * D_ / 4; i += 256) {
      float4 v = src[i];
      h2_t p0; p0.x = (_Float16)v.x; p0.y = (_Float16)v.y;
      h2_t p1; p1.x = (_Float16)v.z; p1.y = (_Float16)v.w;
      dst[2 * i]     = p0;
      dst[2 * i + 1] = p1;
    }
  }
  __syncthreads();

  _Float16* outb = xw + ((size_t)dir * B_ * T_ + bt0) * G_ + 2 * tid;
  for (int row = 0; row < 128; ++row) {
    const float4* xr4 = (const float4*)(xsh + row * D_);   // 10 chunks of 4 h2
    float s0 = 0.f, s1 = 0.f, s2 = 0.f, s3 = 0.f;
    #pragma unroll
    for (int ch = 0; ch < 10; ++ch) {
      float4 f = xr4[ch];
      h2_t q0 = asH2_(f.x), q1 = asH2_(f.y), q2 = asH2_(f.z), q3 = asH2_(f.w);
      s0 = fdot2_(wa[4 * ch],     q0, s0);
      s1 = fdot2_(wa[4 * ch + 1], q1, s1);
      s0 = fdot2_(wa[4 * ch + 2], q2, s0);
      s1 = fdot2_(wa[4 * ch + 3], q3, s1);
      s2 = fdot2_(wb[4 * ch],     q0, s2);
      s3 = fdot2_(wb[4 * ch + 1], q1, s3);
      s2 = fdot2_(wb[4 * ch + 2], q2, s2);
      s3 = fdot2_(wb[4 * ch + 3], q3, s3);
    }
    h2_t o; o.x = (_Float16)(s0 + s1); o.y = (_Float16)(s2 + s3);
    *(h2_t*)(outb + (size_t)row * G_) = o;   // 4B store, lanes contiguous
  }
}

// ---------------------------------------------------------------------------
// Recurrent LSTM, R=2: grid 128 (one WG per (b,dir), 1 WG/CU), 256 threads.
// Thread (u = tid&127, half = tid>>7) owns gate rows:
//   half==0: i-row u       and g-row 256+u
//   half==1: f-row 128+u   and o-row 384+u
// Whh rows f16x2 register-resident (2*64 = 128 VGPRs). Per step each thread
// reads the shared h vector ONCE (16 ds_read_b128 broadcast) and feeds both
// rows -> per-CU LDS pipe = 4 waves * 16 * 12 = 768 cyc/step (vs 2496 at R=1,
// the measured R5 bottleneck).
// Nonlinearity: half0 writes sig(i)*tanh(g) to LDS; half1 owns c and h.
// h stores are register-buffered 8 steps (no per-step vmcnt store drain).
// ---------------------------------------------------------------------------
template<int USE_XW>
__global__ __launch_bounds__(256)
void lstm_kernel(const float* __restrict__ x,
                 const float* __restrict__ Wih_f, const float* __restrict__ Whh_f,
                 const float* __restrict__ bih_f, const float* __restrict__ bhh_f,
                 const float* __restrict__ Wih_b, const float* __restrict__ Whh_b,
                 const float* __restrict__ bih_b, const float* __restrict__ bhh_b,
                 const _Float16* __restrict__ xw,
                 _Float16* __restrict__ hcat)
{
  const int bb  = blockIdx.x & 63;
  const int dir = blockIdx.x >> 6;
  const float* Whh = dir ? Whh_b : Whh_f;
  const float* Wih = dir ? Wih_b : Wih_f;
  const float* bih = dir ? bih_b : bih_f;
  const float* bhh = dir ? bhh_b : bhh_f;

  const int tid  = threadIdx.x;     // 0..255
  const int u    = tid & 127;
  const int half = tid >> 7;        // wave-uniform
  const int r0   = half * H_ + u;           // i or f row
  const int r1   = 2 * H_ + half * H_ + u;  // g or o row

  h2_t w0[H_ / 2], w1[H_ / 2];
  #pragma unroll
  for (int j = 0; j < H_ / 2; ++j) {
    const float* a = Whh + (size_t)r0 * H_ + 2 * j;
    const float* d = Whh + (size_t)r1 * H_ + 2 * j;
    h2_t v0; v0.x = (_Float16)a[0]; v0.y = (_Float16)a[1]; w0[j] = v0;
    h2_t v1; v1.x = (_Float16)d[0]; v1.y = (_Float16)d[1]; w1[j] = v1;
  }
  h2_t wx0[D_ / 2], wx1[D_ / 2];
  if (!USE_XW) {
    #pragma unroll
    for (int i = 0; i < D_ / 2; ++i) {
      const float* a = Wih + (size_t)r0 * D_ + 2 * i;
      const float* d = Wih + (size_t)r1 * D_ + 2 * i;
      h2_t v0; v0.x = (_Float16)a[0]; v0.y = (_Float16)a[1]; wx0[i] = v0;
      h2_t v1; v1.x = (_Float16)d[0]; v1.y = (_Float16)d[1]; wx1[i] = v1;
    }
  }
  const float bias0 = bih[r0] + bhh[r0];
  const float bias1 = bih[r1] + bhh[r1];

  __shared__ alignas(16) _Float16 hs[H_];
  __shared__ alignas(16) _Float16 xs[D_];
  __shared__ float ig[H_];          // sig(i)*tanh(g), written by half0

  if (tid < H_) hs[tid] = (_Float16)0.0f;
  float c = 0.0f;                   // half1 owns cell state of unit u
  _Float16 hbuf[8];

  const float*    xb  = x + (size_t)bb * T_ * D_;
  const _Float16* xwb = xw + ((size_t)dir * B_ * T_ + (size_t)bb * T_) * G_;
  _Float16*       hb  = hcat + (size_t)bb * T_ * (2 * H_) + dir * H_;

  const int t0 = dir ? (T_ - 1) : 0;
  _Float16 xw0p = (_Float16)0.0f, xw1p = (_Float16)0.0f;
  if (USE_XW) {
    xw0p = xwb[(size_t)t0 * G_ + r0];
    xw1p = xwb[(size_t)t0 * G_ + r1];
  } else {
    if (tid < D_) xs[tid] = (_Float16)xb[t0 * D_ + tid];
  }
  __syncthreads();

  for (int tb = 0; tb < T_; tb += 8) {
    // flush previous 8 buffered h (half1); stores get a full 8 steps to drain
    if (half && tb) {
      #pragma unroll
      for (int q = 0; q < 8; ++q) {
        const int ts = tb - 8 + q;
        const int tq = dir ? (T_ - 1 - ts) : ts;
        hb[(size_t)tq * (2 * H_) + u] = hbuf[q];
      }
    }

    #pragma unroll
    for (int q = 0; q < 8; ++q) {
      const int tt = tb + q;
      const int t  = dir ? (T_ - 1 - tt) : tt;
      const int tn = dir ? (t - 1) : (t + 1);

      float a0 = bias0, a1 = 0.f, b0 = bias1, b1 = 0.f;
      float xn = 0.0f;
      if (USE_XW) {
        a0 += (float)xw0p;
        b0 += (float)xw1p;
        if (tt + 1 < T_) {                     // prefetch next step's xw
          xw0p = xwb[(size_t)tn * G_ + r0];
          xw1p = xwb[(size_t)tn * G_ + r1];
        }
      } else {
        if (half == 0 && u < D_ && tt + 1 < T_) xn = xb[tn * D_ + u];
        const float4* xr4 = (const float4*)xs;
        #pragma unroll
        for (int ch = 0; ch < D_ / 8; ++ch) {
          float4 f = xr4[ch];
          h2_t q0 = asH2_(f.x), q1 = asH2_(f.y), q2 = asH2_(f.z), q3 = asH2_(f.w);
          a0 = fdot2_(wx0[4 * ch],     q0, a0);
          a1 = fdot2_(wx0[4 * ch + 1], q1, a1);
          a0 = fdot2_(wx0[4 * ch + 2], q2, a0);
          a1 = fdot2_(wx0[4 * ch + 3], q3, a1);
          b0 = fdot2_(wx1[4 * ch],     q0, b0);
          b1 = fdot2_(wx1[4 * ch + 1], q1, b1);
          b0 = fdot2_(wx1[4 * ch + 2], q2, b0);
          b1 = fdot2_(wx1[4 * ch + 3], q3, b1);
        }
      }

      const float4* hr4 = (const float4*)hs;   // 16 chunks of 4 h2, read ONCE
      #pragma unroll
      for (int ch = 0; ch < H_ / 8; ++ch) {
        float4 f = hr4[ch];
        h2_t q0 = asH2_(f.x), q1 = asH2_(f.y), q2 = asH2_(f.z), q3 = asH2_(f.w);
        a0 = fdot2_(w0[4 * ch],     q0, a0);
        a1 = fdot2_(w0[4 * ch + 1], q1, a1);
        a0 = fdot2_(w0[4 * ch + 2], q2, a0);
        a1 = fdot2_(w0[4 * ch + 3], q3, a1);
        b0 = fdot2_(w1[4 * ch],     q0, b0);
        b1 = fdot2_(w1[4 * ch + 1], q1, b1);
        b0 = fdot2_(w1[4 * ch + 2], q2, b0);
        b1 = fdot2_(w1[4 * ch + 3], q3, b1);
      }
      const float ga = a0 + a1;   // i (half0) or f (half1)
      const float gb = b0 + b1;   // g (half0) or o (half1)

      float sf = 0.f, so = 0.f;
      if (!half) {
        ig[u] = sigf_(ga) * tanhf_(gb);        // parallel with half1's sigs
      } else {
        sf = sigf_(ga);
        so = sigf_(gb);
      }
      __syncthreads();   // ig visible; all hs/xs reads of this step done

      if (half) {
        c = sf * c + ig[u];
        const float h = so * tanhf_(c);
        hs[u]   = (_Float16)h;
        hbuf[q] = (_Float16)h;
      } else if (!USE_XW) {
        if (u < D_ && tt + 1 < T_) xs[u] = (_Float16)xn;
      }
      __syncthreads();   // new hs/xs ready
    }
  }

  if (half) {
    #pragma unroll
    for (int q = 0; q < 8; ++q) {
      const int ts = T_ - 8 + q;
      const int tq = dir ? (T_ - 1 - ts) : ts;
      hb[(size_t)tq * (2 * H_) + u] = hbuf[q];
    }
  }
}

// ---------------------------------------------------------------------------
// Emissions from f16 hcat. 64 bt-rows per block; h tile in LDS (stride 257),
// Wp in LDS (wave-uniform broadcast).
// ---------------------------------------------------------------------------
__global__ __launch_bounds__(256)
void emis_kernel(const _Float16* __restrict__ hcat,
                 const float* __restrict__ Wp, const float* __restrict__ bp,
                 float* __restrict__ em)
{
  __shared__ float sh[64 * 257];
  __shared__ float swp[40 * 256];
  const int tid = threadIdx.x;

  for (int i = tid; i < K_ * 256; i += 256) swp[i] = Wp[i];

  const h2_t* src = (const h2_t*)(hcat + (size_t)blockIdx.x * 64 * 256);
  for (int i = tid; i < 64 * 128; i += 256) {
    h2_t v = src[i];
    int row = i >> 7, col = (i & 127) * 2;
    sh[row * 257 + col]     = (float)v.x;
    sh[row * 257 + col + 1] = (float)v.y;
  }
  __syncthreads();

  const int row = tid & 63;
  const int kq  = tid >> 6;          // wave-uniform
  const float* hrow = &sh[row * 257];

  float accs[10];
  #pragma unroll
  for (int q = 0; q < 10; ++q) {
    int k = kq * 10 + q;
    accs[q] = (k < K_) ? bp[k] : 0.0f;
  }

  for (int j0 = 0; j0 < 256; j0 += 4) {
    float h0 = hrow[j0], h1 = hrow[j0 + 1], hh2 = hrow[j0 + 2], h3 = hrow[j0 + 3];
    #pragma unroll
    for (int q = 0; q < 10; ++q) {
      const float4 w = *(const float4*)&swp[(kq * 10 + q) * 256 + j0];
      accs[q] += h0 * w.x + h1 * w.y + hh2 * w.z + h3 * w.w;
    }
  }

  const size_t bt = (size_t)blockIdx.x * 64 + row;
  #pragma unroll
  for (int q = 0; q < 10; ++q) {
    int k = kq * 10 + q;
    if (k < K_) em[bt * K_ + k] = accs[q];
  }
}

// ---------------------------------------------------------------------------
// Numerator: masked reduction over t per batch element.
// ---------------------------------------------------------------------------
__global__ void crf_num_kernel(const int* __restrict__ labels, const int* __restrict__ lengths,
                               const float* __restrict__ em,
                               const float* __restrict__ start_t, const float* __restrict__ end_t,
                               const float* __restrict__ trans,
                               float* __restrict__ num)
{
  const int b = blockIdx.x;
  const int tid = threadIdx.x;   // 256
  const int len = lengths[b];
  float acc = 0.0f;
  for (int t = 1 + tid; t < len; t += 256) {
    int lp = labels[b * T_ + t - 1];
    int lc = labels[b * T_ + t];
    acc += trans[lp * K_ + lc] + em[((size_t)b * T_ + t) * K_ + lc];
  }
  __shared__ float red[256];
  red[tid] = acc;
  __syncthreads();
  for (int s = 128; s > 0; s >>= 1) {
    if (tid < s) red[tid] += red[tid + s];
    __syncthreads();
  }
  if (tid == 0) {
    int l0 = labels[b * T_];
    int ll = labels[b * T_ + len - 1];
    num[b] = red[0] + start_t[l0] + em[(size_t)b * T_ * K_ + l0] + end_t[ll];
  }
}

// ---------------------------------------------------------------------------
// Denominator: linear-space forward algorithm, one wave per batch element.
// et column register-resident (39 VGPRs); per step 39 readlane-FMA + 1 exp.
// em prefetched FOUR steps ahead in a rotating register pipeline to cover
// the ~200-900 cyc load latency (compute alone is only ~150 cyc/step).
// ---------------------------------------------------------------------------
__global__ void crf_den_kernel(const float* __restrict__ em, const int* __restrict__ lengths,
                               const float* __restrict__ start_t, const float* __restrict__ end_t,
                               const float* __restrict__ trans,
                               float* __restrict__ den)
{
  const int b = blockIdx.x;
  const int k = threadIdx.x;     // 64 threads = 1 wave

  float et[K_];
  #pragma unroll
  for (int j = 0; j < K_; ++j)
    et[j] = (k < K_) ? __expf(trans[j * K_ + k]) : 0.0f;

  const int len = lengths[b];
  const float* emb = em + (size_t)b * T_ * K_;

  float a0 = (k < K_) ? (start_t[k] + emb[k]) : -1e30f;
  float m = a0;
  #pragma unroll
  for (int off = 32; off > 0; off >>= 1) m = fmaxf(m, __shfl_xor(m, off));
  float v = __expf(a0 - m);           // lanes >= 39 -> 0
  float off_acc = m;

  // rotating 4-deep em prefetch pipeline (e0 = em[t], ... e3 = em[t+3])
  auto ld = [&](int t) -> float {
    int tc = (t < len) ? t : (len - 1);
    return (k < K_) ? emb[(size_t)tc * K_ + k] : 0.0f;
  };
  float e0 = ld(1), e1 = ld(2), e2 = ld(3), e3 = ld(4);

  for (int t = 1; t < len; ++t) {
    const float emc = e0;
    e0 = e1; e1 = e2; e2 = e3;
    e3 = ld(t + 4);                   // 4 steps ahead

    const float pv = v;
    float s0 = 0.f, s1 = 0.f, s2 = 0.f, s3 = 0.f;
    #pragma unroll
    for (int j = 0; j < 36; j += 4) {
      s0 = fmaf(laneb_(pv, j),     et[j],     s0);
      s1 = fmaf(laneb_(pv, j + 1), et[j + 1], s1);
      s2 = fmaf(laneb_(pv, j + 2), et[j + 2], s2);
      s3 = fmaf(laneb_(pv, j + 3), et[j + 3], s3);
    }
    s0 = fmaf(laneb_(pv, 36), et[36], s0);
    s1 = fmaf(laneb_(pv, 37), et[37], s1);
    s2 = fmaf(laneb_(pv, 38), et[38], s2);

    v = ((s0 + s1) + (s2 + s3)) * __expf(emc);
    if ((t & 3) == 0) {               // renormalize every 4 steps
      float vm = v;
      #pragma unroll
      for (int off = 32; off > 0; off >>= 1) vm = fmaxf(vm, __shfl_xor(vm, off));
      v *= 1.0f / vm;
      off_acc += __logf(vm);
    }
  }

  float w = (k < K_) ? v * __expf(end_t[k]) : 0.0f;
  #pragma unroll
  for (int off = 32; off > 0; off >>= 1) w += __shfl_xor(w, off);
  if (k == 0) den[b] = off_acc + __logf(w);
}

__global__ void finalize_kernel(const float* __restrict__ num, const float* __restrict__ den,
                                float* __restrict__ out)
{
  const int tid = threadIdx.x;   // 64
  float v = den[tid] - num[tid];
  #pragma unroll
  for (int off = 32; off > 0; off >>= 1) v += __shfl_down(v, off);
  if (tid == 0) out[0] = v * (1.0f / 64.0f);
}

extern "C" void kernel_launch(void* const* d_in, const int* in_sizes, int n_in,
                              void* d_out, int out_size, void* d_ws, size_t ws_size,
                              hipStream_t stream)
{
  (void)in_sizes; (void)n_in; (void)out_size;
  const float* features = (const float*)d_in[0];
  const int*   lengths  = (const int*)d_in[1];
  const int*   labels   = (const int*)d_in[2];
  const float* Wih_f = (const float*)d_in[3];
  const float* Whh_f = (const float*)d_in[4];
  const float* bih_f = (const float*)d_in[5];
  const float* bhh_f = (const float*)d_in[6];
  const float* Wih_b = (const float*)d_in[7];
  const float* Whh_b = (const float*)d_in[8];
  const float* bih_b = (const float*)d_in[9];
  const float* bhh_b = (const float*)d_in[10];
  const float* Wp      = (const float*)d_in[11];
  const float* bp      = (const float*)d_in[12];
  const float* start_t = (const float*)d_in[13];
  const float* end_t   = (const float*)d_in[14];
  const float* trans   = (const float*)d_in[15];
  float* out = (float*)d_out;

  // ws layout (bytes): hcat f16 [0, 26214400) ; em f32 [26214400, +7987200) ;
  // num/den 512 B ; xw f16 [34202112, +104857600) if ws is big enough.
  char* wsc = (char*)d_ws;
  _Float16* hcatH = (_Float16*)wsc;
  float*    em    = (float*)(wsc + 26214400);
  float*    num   = (float*)(wsc + 26214400 + 7987200);
  float*    den   = num + B_;
  _Float16* xwH   = (_Float16*)(wsc + 34202112);
  const bool big  = ws_size >= (size_t)34202112 + 104857600;

  if (big) {
    hipLaunchKernelGGL(xw_kernel, dim3(2 * B_ * T_ / 128), dim3(256), 0, stream,
                       features, Wih_f, Wih_b, xwH);
    hipLaunchKernelGGL((lstm_kernel<1>), dim3(2 * B_), dim3(256), 0, stream,
                       features, Wih_f, Whh_f, bih_f, bhh_f,
                       Wih_b, Whh_b, bih_b, bhh_b, xwH, hcatH);
  } else {
    hipLaunchKernelGGL((lstm_kernel<0>), dim3(2 * B_), dim3(256), 0, stream,
                       features, Wih_f, Whh_f, bih_f, bhh_f,
                       Wih_b, Whh_b, bih_b, bhh_b, xwH, hcatH);
  }
  hipLaunchKernelGGL(emis_kernel, dim3(B_ * T_ / 64), dim3(256), 0, stream,
                     hcatH, Wp, bp, em);
  hipLaunchKernelGGL(crf_num_kernel, dim3(B_), dim3(256), 0, stream,
                     labels, lengths, em, start_t, end_t, trans, num);
  hipLaunchKernelGGL(crf_den_kernel, dim3(B_), dim3(64), 0, stream,
                     em, lengths, start_t, end_t, trans, den);
  hipLaunchKernelGGL(finalize_kernel, dim3(1), dim3(64), 0, stream,
                     num, den, out);
}